// Round 8
// baseline (209.696 us; speedup 1.0000x reference)
//
#include <hip/hip_runtime.h>
#include <hip/hip_cooperative_groups.h>
#include <hip/hip_bf16.h>
#include <stdint.h>
#include <math.h>

// ---------------------------------------------------------------------------
// LinkPredictor: out = minmax_norm(E @ E^T)[block-diag strict upper triangle]
// N=16384 (128 graphs x 128), D=512.
// R8: single cooperative mega-kernel (convert -> i8/diag GEMM -> self-flagged
// bf16 refine -> gather) with grid.sync() between phases. Kills the ~50us of
// inter-dispatch boundaries that stayed constant across R1-R7. Grid sized by
// occupancy query (never over-subscribes); falls back to the proven R7
// 5-kernel path if cooperative launch is unavailable.
// ---------------------------------------------------------------------------

namespace cg = cooperative_groups;

typedef __attribute__((ext_vector_type(8))) __bf16 bf16x8;
typedef __attribute__((ext_vector_type(16))) float floatx16;
typedef __attribute__((ext_vector_type(4))) int intx4;
typedef __attribute__((ext_vector_type(16))) int intx16;

#define AS1 __attribute__((address_space(1)))
#define AS3 __attribute__((address_space(3)))

static constexpr int DIM      = 512;
static constexpr int NTILE    = 128;
static constexpr int NPART    = NTILE * (NTILE + 1) / 2;  // 8256 tiles
static constexpr int CAP      = 512;                      // fallback refine cap
static constexpr float QS     = 19.5f;                    // i8 quant scale
static constexpr int MARGIN_I = 3042;                     // 8 sims-units * QS^2

// ctrl: [0] fkey_min [1] fkey_max [2] i8 gmin [3] unused [4] refine count

static __device__ __forceinline__ unsigned short f2bf_rne(float f) {
  unsigned int u = __float_as_uint(f);
  u += 0x7fffu + ((u >> 16) & 1u);
  return (unsigned short)(u >> 16);
}
static __device__ __forceinline__ int fkey(float f) {
  int s = __float_as_int(f);
  return s >= 0 ? s : (s ^ 0x7fffffff);
}
static __device__ __forceinline__ float funkey(int k) {
  return __int_as_float(k >= 0 ? k : (k ^ 0x7fffffff));
}
// i8 BK=128: 8 chunks(16B)/row
static __device__ __forceinline__ int swzi(int row, int c8) {
  return c8 ^ (row & 7) ^ ((row >> 3) & 7);
}
// bf16 BK=128 (diag): 16 chunks(16B)/row
static __device__ __forceinline__ int swzd(int row, int c16) {
  return c16 ^ (row & 15);
}
// bf16 BK=64 (refine): 8 chunks(16B)/row
static __device__ __forceinline__ int swz8(int row, int c8) {
  return c8 ^ (row & 7);
}
static __device__ __forceinline__ void tri_decode(int bi, int& tr_, int& tc_) {
  int t = (int)((257.0 - sqrt(66049.0 - 8.0 * (double)bi)) * 0.5);
  if (t < 0) t = 0;
  if (t > 127) t = 127;
  while (t * (257 - t) / 2 > bi) --t;
  while (t < 127 && (t + 1) * (256 - t) / 2 <= bi) ++t;
  tr_ = t;
  tc_ = t + (bi - t * (257 - t) / 2);
}

// ============================================================================
// Mega-kernel (cooperative): all phases in one dispatch.
// ============================================================================
__global__ __launch_bounds__(256) void k_mega(
    const float* __restrict__ in,
    unsigned short* __restrict__ Ebf,
    char* __restrict__ Eq,
    int2* __restrict__ ipart,
    float* __restrict__ diagblocks,
    int* __restrict__ ctrl,
    const int* __restrict__ rix,
    const int* __restrict__ cix,
    float* __restrict__ out,
    int out_size, int n4) {
  cg::grid_group grid = cg::this_grid();

  __shared__ __align__(16) char smem[2][16384];   // 32 KB, re-used per phase
  __shared__ float2 redbuf[4];
  __shared__ int2 iredbuf[4];

  const int tid = threadIdx.x;
  const int w = tid >> 6, lane = tid & 63;
  const int wr = w >> 1, wc = w & 1;
  const int l31 = lane & 31;
  const int kg  = lane >> 5;
  const int gstride = gridDim.x * blockDim.x;

  // ---------------- P0: init ctrl + fp32 -> bf16 + i8 ----------------
  if (blockIdx.x == 0 && tid == 0) {
    ctrl[0] = 0x7fffffff; ctrl[1] = (int)0x80000000;
    ctrl[2] = 0x7fffffff; ctrl[3] = (int)0x80000000;
    ctrl[4] = 0;
  }
  for (int i = blockIdx.x * blockDim.x + tid; i < n4; i += gstride) {
    float4 v = ((const float4*)in)[i];
    ushort4 o;
    o.x = f2bf_rne(v.x); o.y = f2bf_rne(v.y);
    o.z = f2bf_rne(v.z); o.w = f2bf_rne(v.w);
    ((ushort4*)Ebf)[i] = o;
    int qx = __float2int_rn(v.x * QS), qy = __float2int_rn(v.y * QS);
    int qz = __float2int_rn(v.z * QS), qw = __float2int_rn(v.w * QS);
    char4 c;
    c.x = (char)min(127, max(-127, qx));
    c.y = (char)min(127, max(-127, qy));
    c.z = (char)min(127, max(-127, qz));
    c.w = (char)min(127, max(-127, qw));
    ((char4*)Eq)[i] = c;
  }
  __threadfence();
  grid.sync();

  // ---------------- P1: GEMM over 8256 upper-tri tiles ----------------
  for (int bi = blockIdx.x; bi < NPART; bi += gridDim.x) {
    int tr, tc;
    tri_decode(bi, tr, tc);

    if (tr != tc) {
      // ---- i8 path (min localization), BK=128 ----
      char* lA8 = smem[0];
      char* lB8 = smem[1];
      intx16 acc[2][2];
#pragma unroll
      for (int i = 0; i < 2; i++)
#pragma unroll
        for (int j = 0; j < 2; j++)
#pragma unroll
          for (int r = 0; r < 16; r++) acc[i][j][r] = 0;

      const int rowBaseA = tr * 128;
      const int rowBaseB = tc * 128;

      for (int kb = 0; kb < 4; kb++) {          // K = 512 = 4 * 128
        const int kBase = kb * 128;
#pragma unroll
        for (int j = 0; j < 4; j++) {
          int cb  = (w * 4 + j) * 64;
          int p   = cb + lane;
          int row = p >> 3, c8 = p & 7;
          int sc8 = swzi(row, c8);
          const char* gA = Eq + (size_t)(rowBaseA + row) * DIM + kBase + sc8 * 16;
          const char* gB = Eq + (size_t)(rowBaseB + row) * DIM + kBase + sc8 * 16;
          __builtin_amdgcn_global_load_lds((const AS1 unsigned int*)gA,
                                           (AS3 unsigned int*)(lA8 + p * 16), 16, 0, 0);
          __builtin_amdgcn_global_load_lds((const AS1 unsigned int*)gB,
                                           (AS3 unsigned int*)(lB8 + p * 16), 16, 0, 0);
        }
        __syncthreads();

#pragma unroll
        for (int ks = 0; ks < 4; ks++) {        // 4 k-steps of 32
          intx4 af[2], bfv[2];
          const int c8 = ks * 2 + kg;
#pragma unroll
          for (int t = 0; t < 2; t++) {
            int ra = wr * 64 + t * 32 + l31;
            int rb = wc * 64 + t * 32 + l31;
            af[t]  = *(const intx4*)(lA8 + ra * 128 + swzi(ra, c8) * 16);
            bfv[t] = *(const intx4*)(lB8 + rb * 128 + swzi(rb, c8) * 16);
          }
#pragma unroll
          for (int ti = 0; ti < 2; ti++)
#pragma unroll
            for (int tj = 0; tj < 2; tj++)
              acc[ti][tj] = __builtin_amdgcn_mfma_i32_32x32x32_i8(
                  af[ti], bfv[tj], acc[ti][tj], 0, 0, 0);
        }
        __syncthreads();
      }

      int vmin = 0x7fffffff;
#pragma unroll
      for (int ti = 0; ti < 2; ti++)
#pragma unroll
        for (int tj = 0; tj < 2; tj++)
#pragma unroll
          for (int r = 0; r < 16; r++) vmin = min(vmin, acc[ti][tj][r]);
#pragma unroll
      for (int m_ = 32; m_ >= 1; m_ >>= 1)
        vmin = min(vmin, __shfl_xor(vmin, m_));
      if (lane == 0) iredbuf[w] = make_int2(vmin, 0);
      __syncthreads();
      if (tid == 0) {
        int mn = iredbuf[0].x;
        for (int i = 1; i < 4; i++) mn = min(mn, iredbuf[i].x);
        ipart[bi] = make_int2(mn, 0);
        atomicMin(&ctrl[2], mn);
      }
    } else {
      // ---- bf16 diagonal path (exact), BK=128 ----
      unsigned short* lA = (unsigned short*)&smem[0][0];  // 32 KB contiguous
      floatx16 acc[2][2];
#pragma unroll
      for (int i = 0; i < 2; i++)
#pragma unroll
        for (int j = 0; j < 2; j++)
#pragma unroll
          for (int r = 0; r < 16; r++) acc[i][j][r] = 0.f;

      const int rowBase = tr * 128;

      for (int kb = 0; kb < 4; kb++) {
        const int kBase = kb * 128;
#pragma unroll
        for (int j = 0; j < 8; j++) {
          int cb  = (w * 8 + j) * 64;
          int p   = cb + lane;
          int row = p >> 4, c16 = p & 15;
          int sc = swzd(row, c16);
          const unsigned short* gA =
              Ebf + (size_t)(rowBase + row) * DIM + kBase + sc * 8;
          __builtin_amdgcn_global_load_lds((const AS1 unsigned int*)gA,
                                           (AS3 unsigned int*)(lA + p * 8), 16, 0, 0);
        }
        __syncthreads();

#pragma unroll
        for (int ks = 0; ks < 8; ks++) {
          bf16x8 af[2], bfv[2];
          const int c16 = ks * 2 + kg;
#pragma unroll
          for (int t = 0; t < 2; t++) {
            int ra = wr * 64 + t * 32 + l31;
            int rb = wc * 64 + t * 32 + l31;
            af[t]  = *(const bf16x8*)(lA + ra * 128 + swzd(ra, c16) * 8);
            bfv[t] = *(const bf16x8*)(lA + rb * 128 + swzd(rb, c16) * 8);
          }
#pragma unroll
          for (int ti = 0; ti < 2; ti++)
#pragma unroll
            for (int tj = 0; tj < 2; tj++)
              acc[ti][tj] = __builtin_amdgcn_mfma_f32_32x32x16_bf16(
                  af[ti], bfv[tj], acc[ti][tj], 0, 0, 0);
        }
        __syncthreads();
      }

      float vmin = 3.4e38f, vmax = -3.4e38f;
#pragma unroll
      for (int ti = 0; ti < 2; ti++)
#pragma unroll
        for (int tj = 0; tj < 2; tj++)
#pragma unroll
          for (int r = 0; r < 16; r++) {
            float v = acc[ti][tj][r];
            vmin = fminf(vmin, v);
            vmax = fmaxf(vmax, v);
          }
#pragma unroll
      for (int m_ = 32; m_ >= 1; m_ >>= 1) {
        vmin = fminf(vmin, __shfl_xor(vmin, m_));
        vmax = fmaxf(vmax, __shfl_xor(vmax, m_));
      }
      if (lane == 0) redbuf[w] = make_float2(vmin, vmax);
      __syncthreads();
      if (tid == 0) {
        float mn = redbuf[0].x, mx = redbuf[0].y;
        for (int i = 1; i < 4; i++) {
          mn = fminf(mn, redbuf[i].x);
          mx = fmaxf(mx, redbuf[i].y);
        }
        atomicMin(&ctrl[0], fkey(mn));
        atomicMax(&ctrl[1], fkey(mx));  // global max is diagonal (Cauchy-Schwarz)
        ipart[bi] = make_int2(0x7fffffff, 0);  // never flagged
      }

      float* Bout = diagblocks + (size_t)tr * (128 * 128);
#pragma unroll
      for (int ti = 0; ti < 2; ti++) {
#pragma unroll
        for (int tj = 0; tj < 2; tj++) {
          int cbase = wc * 64 + tj * 32 + l31;   // C/D: col = lane & 31
#pragma unroll
          for (int r = 0; r < 16; r++) {
            int row = wr * 64 + ti * 32 + (r & 3) + 8 * (r >> 2) + 4 * kg;
            Bout[row * 128 + cbase] = acc[ti][tj][r];
          }
        }
      }
    }
    __syncthreads();
  }
  __threadfence();
  grid.sync();

  // ---------------- P2: self-flagged bf16 refine (exact min) ----------------
  {
    const int gmin = ctrl[2];
    for (int bi = blockIdx.x; bi < NPART; bi += gridDim.x) {
      if (ipart[bi].x > gmin + MARGIN_I) continue;   // block-uniform branch
      int tr, tc;
      tri_decode(bi, tr, tc);
      unsigned short* lA = (unsigned short*)&smem[0][0];  // 128x64 bf16
      unsigned short* lB = (unsigned short*)&smem[1][0];
      floatx16 acc[2][2];
#pragma unroll
      for (int i = 0; i < 2; i++)
#pragma unroll
        for (int j = 0; j < 2; j++)
#pragma unroll
          for (int r = 0; r < 16; r++) acc[i][j][r] = 0.f;

      const int rowBaseA = tr * 128;
      const int rowBaseB = tc * 128;

      for (int kb = 0; kb < 8; kb++) {          // BK=64
        const int kBase = kb * 64;
#pragma unroll
        for (int j = 0; j < 4; j++) {
          int cb  = (w * 4 + j) * 64;
          int p   = cb + lane;
          int row = p >> 3, c8 = p & 7;
          int sc8 = swz8(row, c8);
          const unsigned short* gA = Ebf + (size_t)(rowBaseA + row) * DIM + kBase + sc8 * 8;
          const unsigned short* gB = Ebf + (size_t)(rowBaseB + row) * DIM + kBase + sc8 * 8;
          __builtin_amdgcn_global_load_lds((const AS1 unsigned int*)gA,
                                           (AS3 unsigned int*)(lA + cb * 8), 16, 0, 0);
          __builtin_amdgcn_global_load_lds((const AS1 unsigned int*)gB,
                                           (AS3 unsigned int*)(lB + cb * 8), 16, 0, 0);
        }
        __syncthreads();

#pragma unroll
        for (int ks = 0; ks < 4; ks++) {
          bf16x8 af[2], bfv[2];
          const int c8 = ks * 2 + kg;
#pragma unroll
          for (int t = 0; t < 2; t++) {
            int ra = wr * 64 + t * 32 + l31;
            int rb = wc * 64 + t * 32 + l31;
            af[t]  = *(const bf16x8*)(lA + (ra * 8 + swz8(ra, c8)) * 8);
            bfv[t] = *(const bf16x8*)(lB + (rb * 8 + swz8(rb, c8)) * 8);
          }
#pragma unroll
          for (int ti = 0; ti < 2; ti++)
#pragma unroll
            for (int tj = 0; tj < 2; tj++)
              acc[ti][tj] = __builtin_amdgcn_mfma_f32_32x32x16_bf16(
                  af[ti], bfv[tj], acc[ti][tj], 0, 0, 0);
        }
        __syncthreads();
      }

      float vmin = 3.4e38f;
#pragma unroll
      for (int ti = 0; ti < 2; ti++)
#pragma unroll
        for (int tj = 0; tj < 2; tj++)
#pragma unroll
          for (int r = 0; r < 16; r++) vmin = fminf(vmin, acc[ti][tj][r]);
#pragma unroll
      for (int m_ = 32; m_ >= 1; m_ >>= 1)
        vmin = fminf(vmin, __shfl_xor(vmin, m_));
      if (lane == 0) redbuf[w] = make_float2(vmin, 0.f);
      __syncthreads();
      if (tid == 0) {
        float mn = redbuf[0].x;
        for (int i = 1; i < 4; i++) mn = fminf(mn, redbuf[i].x);
        atomicMin(&ctrl[0], fkey(mn));
      }
      __syncthreads();
    }
  }
  __threadfence();
  grid.sync();

  // ---------------- P3: gather + normalize ----------------
  {
    const float m   = funkey(ctrl[0]);
    const float M   = funkey(ctrl[1]);
    const float inv = 1.0f / (M - m + 1e-7f);
    for (int i = blockIdx.x * blockDim.x + tid; i < out_size; i += gstride) {
      int r = rix[i], c = cix[i];
      int g = r >> 7;
      float v = diagblocks[((size_t)g << 14) + ((r & 127) << 7) + (c & 127)];
      out[i] = (v - m) * inv;
    }
  }
}

// ============================================================================
// Fallback path: R7's proven 5-kernel pipeline (used if coop launch fails).
// ============================================================================
__global__ void k_convert(const float* __restrict__ in,
                          unsigned short* __restrict__ bf,
                          char* __restrict__ q,
                          int* __restrict__ ctrl, int n4) {
  int i = blockIdx.x * blockDim.x + threadIdx.x;
  if (i == 0) {
    ctrl[0] = 0x7fffffff; ctrl[1] = (int)0x80000000;
    ctrl[2] = 0x7fffffff; ctrl[3] = (int)0x80000000;
    ctrl[4] = 0;
  }
  if (i >= n4) return;
  float4 v = ((const float4*)in)[i];
  ushort4 o;
  o.x = f2bf_rne(v.x); o.y = f2bf_rne(v.y);
  o.z = f2bf_rne(v.z); o.w = f2bf_rne(v.w);
  ((ushort4*)bf)[i] = o;
  int qx = __float2int_rn(v.x * QS), qy = __float2int_rn(v.y * QS);
  int qz = __float2int_rn(v.z * QS), qw = __float2int_rn(v.w * QS);
  char4 c;
  c.x = (char)min(127, max(-127, qx));
  c.y = (char)min(127, max(-127, qy));
  c.z = (char)min(127, max(-127, qz));
  c.w = (char)min(127, max(-127, qw));
  ((char4*)q)[i] = c;
}

__global__ __launch_bounds__(256) void k_gemm(
    const char* __restrict__ Eq,
    const unsigned short* __restrict__ E,
    int2* __restrict__ ipartials,
    float* __restrict__ diagblocks,
    int* __restrict__ ctrl) {
  int tr, tc;
  tri_decode(blockIdx.x, tr, tc);

  const int tid = threadIdx.x;
  __shared__ __align__(16) char smem[2][16384];
  __shared__ float2 redbuf[4];
  __shared__ int2 iredbuf[4];

  const int w = tid >> 6, lane = tid & 63;
  const int wr = w >> 1, wc = w & 1;
  const int l31 = lane & 31;
  const int kg  = lane >> 5;

  if (tr != tc) {
    char* lA8 = smem[0];
    char* lB8 = smem[1];
    intx16 acc[2][2];
#pragma unroll
    for (int i = 0; i < 2; i++)
#pragma unroll
      for (int j = 0; j < 2; j++)
#pragma unroll
        for (int r = 0; r < 16; r++) acc[i][j][r] = 0;

    const int rowBaseA = tr * 128;
    const int rowBaseB = tc * 128;

    for (int kb = 0; kb < 4; kb++) {
      const int kBase = kb * 128;
#pragma unroll
      for (int j = 0; j < 4; j++) {
        int cb  = (w * 4 + j) * 64;
        int p   = cb + lane;
        int row = p >> 3, c8 = p & 7;
        int sc8 = swzi(row, c8);
        const char* gA = Eq + (size_t)(rowBaseA + row) * DIM + kBase + sc8 * 16;
        const char* gB = Eq + (size_t)(rowBaseB + row) * DIM + kBase + sc8 * 16;
        __builtin_amdgcn_global_load_lds((const AS1 unsigned int*)gA,
                                         (AS3 unsigned int*)(lA8 + p * 16), 16, 0, 0);
        __builtin_amdgcn_global_load_lds((const AS1 unsigned int*)gB,
                                         (AS3 unsigned int*)(lB8 + p * 16), 16, 0, 0);
      }
      __syncthreads();

#pragma unroll
      for (int ks = 0; ks < 4; ks++) {
        intx4 af[2], bfv[2];
        const int c8 = ks * 2 + kg;
#pragma unroll
        for (int t = 0; t < 2; t++) {
          int ra = wr * 64 + t * 32 + l31;
          int rb = wc * 64 + t * 32 + l31;
          af[t]  = *(const intx4*)(lA8 + ra * 128 + swzi(ra, c8) * 16);
          bfv[t] = *(const intx4*)(lB8 + rb * 128 + swzi(rb, c8) * 16);
        }
#pragma unroll
        for (int ti = 0; ti < 2; ti++)
#pragma unroll
          for (int tj = 0; tj < 2; tj++)
            acc[ti][tj] = __builtin_amdgcn_mfma_i32_32x32x32_i8(
                af[ti], bfv[tj], acc[ti][tj], 0, 0, 0);
      }
      __syncthreads();
    }

    int vmin = 0x7fffffff;
#pragma unroll
    for (int ti = 0; ti < 2; ti++)
#pragma unroll
      for (int tj = 0; tj < 2; tj++)
#pragma unroll
        for (int r = 0; r < 16; r++) vmin = min(vmin, acc[ti][tj][r]);
#pragma unroll
    for (int m_ = 32; m_ >= 1; m_ >>= 1)
      vmin = min(vmin, __shfl_xor(vmin, m_));
    if (lane == 0) iredbuf[w] = make_int2(vmin, 0);
    __syncthreads();
    if (tid == 0) {
      int mn = iredbuf[0].x;
      for (int i = 1; i < 4; i++) mn = min(mn, iredbuf[i].x);
      ipartials[blockIdx.x] = make_int2(mn, 0);
      atomicMin(&ctrl[2], mn);
    }
  } else {
    unsigned short* lA = (unsigned short*)&smem[0][0];
    floatx16 acc[2][2];
#pragma unroll
    for (int i = 0; i < 2; i++)
#pragma unroll
      for (int j = 0; j < 2; j++)
#pragma unroll
        for (int r = 0; r < 16; r++) acc[i][j][r] = 0.f;

    const int rowBase = tr * 128;

    for (int kb = 0; kb < 4; kb++) {
      const int kBase = kb * 128;
#pragma unroll
      for (int j = 0; j < 8; j++) {
        int cb  = (w * 8 + j) * 64;
        int p   = cb + lane;
        int row = p >> 4, c16 = p & 15;
        int sc = swzd(row, c16);
        const unsigned short* gA =
            E + (size_t)(rowBase + row) * DIM + kBase + sc * 8;
        __builtin_amdgcn_global_load_lds((const AS1 unsigned int*)gA,
                                         (AS3 unsigned int*)(lA + p * 8), 16, 0, 0);
      }
      __syncthreads();

#pragma unroll
      for (int ks = 0; ks < 8; ks++) {
        bf16x8 af[2], bfv[2];
        const int c16 = ks * 2 + kg;
#pragma unroll
        for (int t = 0; t < 2; t++) {
          int ra = wr * 64 + t * 32 + l31;
          int rb = wc * 64 + t * 32 + l31;
          af[t]  = *(const bf16x8*)(lA + ra * 128 + swzd(ra, c16) * 8);
          bfv[t] = *(const bf16x8*)(lA + rb * 128 + swzd(rb, c16) * 8);
        }
#pragma unroll
        for (int ti = 0; ti < 2; ti++)
#pragma unroll
          for (int tj = 0; tj < 2; tj++)
            acc[ti][tj] = __builtin_amdgcn_mfma_f32_32x32x16_bf16(
                af[ti], bfv[tj], acc[ti][tj], 0, 0, 0);
      }
      __syncthreads();
    }

    float vmin = 3.4e38f, vmax = -3.4e38f;
#pragma unroll
    for (int ti = 0; ti < 2; ti++)
#pragma unroll
      for (int tj = 0; tj < 2; tj++)
#pragma unroll
        for (int r = 0; r < 16; r++) {
          float v = acc[ti][tj][r];
          vmin = fminf(vmin, v);
          vmax = fmaxf(vmax, v);
        }
#pragma unroll
    for (int m_ = 32; m_ >= 1; m_ >>= 1) {
      vmin = fminf(vmin, __shfl_xor(vmin, m_));
      vmax = fmaxf(vmax, __shfl_xor(vmax, m_));
    }
    if (lane == 0) redbuf[w] = make_float2(vmin, vmax);
    __syncthreads();
    if (tid == 0) {
      float mn = redbuf[0].x, mx = redbuf[0].y;
      for (int i = 1; i < 4; i++) {
        mn = fminf(mn, redbuf[i].x);
        mx = fmaxf(mx, redbuf[i].y);
      }
      atomicMin(&ctrl[0], fkey(mn));
      atomicMax(&ctrl[1], fkey(mx));
      ipartials[blockIdx.x] = make_int2(0x7fffffff, 0);
    }

    float* Bout = diagblocks + (size_t)tr * (128 * 128);
#pragma unroll
    for (int ti = 0; ti < 2; ti++) {
#pragma unroll
      for (int tj = 0; tj < 2; tj++) {
        int cbase = wc * 64 + tj * 32 + l31;
#pragma unroll
        for (int r = 0; r < 16; r++) {
          int row = wr * 64 + ti * 32 + (r & 3) + 8 * (r >> 2) + 4 * kg;
          Bout[row * 128 + cbase] = acc[ti][tj][r];
        }
      }
    }
  }
}

__global__ void k_flag(const int2* __restrict__ ipartials,
                       int* __restrict__ ctrl, int* __restrict__ list) {
  int i = blockIdx.x * blockDim.x + threadIdx.x;
  if (i >= NPART) return;
  int gmin = ctrl[2];
  if (ipartials[i].x <= gmin + MARGIN_I) {
    int pos = atomicAdd(&ctrl[4], 1);
    if (pos < CAP) {
      int tr, tc;
      tri_decode(i, tr, tc);
      list[pos] = (tr << 8) | tc;
    }
  }
}

__global__ __launch_bounds__(256) void k_refine(
    const unsigned short* __restrict__ E,
    const int* __restrict__ list, int* __restrict__ ctrl) {
  int cnt = ctrl[4];
  if (cnt > CAP) cnt = CAP;
  if ((int)blockIdx.x >= cnt) return;
  const int enc = list[blockIdx.x];
  const int tr = enc >> 8, tc = enc & 255;

  const int tid = threadIdx.x;
  __shared__ __align__(16) unsigned short lA[128 * 64];
  __shared__ __align__(16) unsigned short lB[128 * 64];
  __shared__ float2 redbuf[4];

  const int w = tid >> 6, lane = tid & 63;
  const int wr = w >> 1, wc = w & 1;
  const int l31 = lane & 31;
  const int kg  = lane >> 5;

  floatx16 acc[2][2];
#pragma unroll
  for (int i = 0; i < 2; i++)
#pragma unroll
    for (int j = 0; j < 2; j++)
#pragma unroll
      for (int r = 0; r < 16; r++) acc[i][j][r] = 0.f;

  const int rowBaseA = tr * 128;
  const int rowBaseB = tc * 128;

  for (int kb = 0; kb < 8; kb++) {
    const int kBase = kb * 64;
#pragma unroll
    for (int j = 0; j < 4; j++) {
      int cb  = (w * 4 + j) * 64;
      int p   = cb + lane;
      int row = p >> 3, c8 = p & 7;
      int sc8 = swz8(row, c8);
      const unsigned short* gA = E + (size_t)(rowBaseA + row) * DIM + kBase + sc8 * 8;
      const unsigned short* gB = E + (size_t)(rowBaseB + row) * DIM + kBase + sc8 * 8;
      __builtin_amdgcn_global_load_lds((const AS1 unsigned int*)gA,
                                       (AS3 unsigned int*)(lA + cb * 8), 16, 0, 0);
      __builtin_amdgcn_global_load_lds((const AS1 unsigned int*)gB,
                                       (AS3 unsigned int*)(lB + cb * 8), 16, 0, 0);
    }
    __syncthreads();

#pragma unroll
    for (int ks = 0; ks < 4; ks++) {
      bf16x8 af[2], bfv[2];
      const int c8 = ks * 2 + kg;
#pragma unroll
      for (int t = 0; t < 2; t++) {
        int ra = wr * 64 + t * 32 + l31;
        int rb = wc * 64 + t * 32 + l31;
        af[t]  = *(const bf16x8*)(lA + (ra * 8 + swz8(ra, c8)) * 8);
        bfv[t] = *(const bf16x8*)(lB + (rb * 8 + swz8(rb, c8)) * 8);
      }
#pragma unroll
      for (int ti = 0; ti < 2; ti++)
#pragma unroll
        for (int tj = 0; tj < 2; tj++)
          acc[ti][tj] = __builtin_amdgcn_mfma_f32_32x32x16_bf16(
              af[ti], bfv[tj], acc[ti][tj], 0, 0, 0);
    }
    __syncthreads();
  }

  float vmin = 3.4e38f;
#pragma unroll
  for (int ti = 0; ti < 2; ti++)
#pragma unroll
    for (int tj = 0; tj < 2; tj++)
#pragma unroll
      for (int r = 0; r < 16; r++) vmin = fminf(vmin, acc[ti][tj][r]);
#pragma unroll
  for (int m_ = 32; m_ >= 1; m_ >>= 1)
    vmin = fminf(vmin, __shfl_xor(vmin, m_));
  if (lane == 0) redbuf[w] = make_float2(vmin, 0.f);
  __syncthreads();
  if (tid == 0) {
    float mn = redbuf[0].x;
    for (int i = 1; i < 4; i++) mn = fminf(mn, redbuf[i].x);
    atomicMin(&ctrl[0], fkey(mn));
  }
}

__global__ __launch_bounds__(256) void k_gather(
    const int* __restrict__ rix, const int* __restrict__ cix,
    const float* __restrict__ blocks, const int* __restrict__ ctrl,
    float* __restrict__ out, int n) {
  int i = blockIdx.x * blockDim.x + threadIdx.x;
  if (i >= n) return;
  float m   = funkey(ctrl[0]);
  float M   = funkey(ctrl[1]);
  float inv = 1.0f / (M - m + 1e-7f);
  int r = rix[i], c = cix[i];
  int g = r >> 7;
  float v = blocks[((size_t)g << 14) + ((r & 127) << 7) + (c & 127)];
  out[i] = (v - m) * inv;
}

// ---------------------------------------------------------------------------
extern "C" void kernel_launch(void* const* d_in, const int* in_sizes, int n_in,
                              void* d_out, int out_size, void* d_ws, size_t ws_size,
                              hipStream_t stream) {
  const float* emb = (const float*)d_in[0];
  const int* rix   = (const int*)d_in[1];
  const int* cix   = (const int*)d_in[2];
  float* outp      = (float*)d_out;

  char* ws = (char*)d_ws;
  int* ctrl           = (int*)ws;                                  // 20 B (pad 256)
  unsigned short* Ebf = (unsigned short*)(ws + 256);               // 16 MB
  char* Eq            = (char*)(ws + 256 + (16u << 20));           // 8 MB
  float* diagblocks   = (float*)(ws + 256 + (24u << 20));          // 8 MB
  int2* ipartials     = (int2*)(ws + 256 + (32u << 20));           // 66 KB
  int* list           = (int*)(ws + 256 + (32u << 20) + (128u << 10)); // 2 KB

  int n4 = in_sizes[0] / 4;            // 16384*512 / 4

  // --- preferred: single cooperative dispatch ---
  int nblk = 0;
  hipError_t qerr = hipOccupancyMaxActiveBlocksPerMultiprocessor(
      &nblk, reinterpret_cast<const void*>(k_mega), 256, 0);
  if (qerr == hipSuccess && nblk > 0) {
    int grid = nblk * 256;             // 256 CUs
    if (grid > 1024) grid = 1024;
    int osz = out_size;
    void* args[] = {(void*)&emb, (void*)&Ebf, (void*)&Eq, (void*)&ipartials,
                    (void*)&diagblocks, (void*)&ctrl, (void*)&rix, (void*)&cix,
                    (void*)&outp, (void*)&osz, (void*)&n4};
    hipError_t lerr = hipLaunchCooperativeKernel(
        reinterpret_cast<const void*>(k_mega), dim3(grid), dim3(256), args, 0,
        stream);
    if (lerr == hipSuccess) return;
  }

  // --- fallback: R7 5-kernel pipeline ---
  k_convert<<<(n4 + 255) / 256, 256, 0, stream>>>(emb, Ebf, Eq, ctrl, n4);
  k_gemm<<<NPART, 256, 0, stream>>>(Eq, Ebf, ipartials, diagblocks, ctrl);
  k_flag<<<(NPART + 255) / 256, 256, 0, stream>>>(ipartials, ctrl, list);
  k_refine<<<CAP, 256, 0, stream>>>(Ebf, list, ctrl);
  k_gather<<<(out_size + 255) / 256, 256, 0, stream>>>(rix, cix, diagblocks,
                                                       ctrl, outp, out_size);
}

// Round 9
// 193.408 us; speedup vs baseline: 1.0842x; 1.0842x over previous
//
#include <hip/hip_runtime.h>
#include <hip/hip_bf16.h>
#include <stdint.h>

// ---------------------------------------------------------------------------
// LinkPredictor: out = minmax_norm(E @ E^T)[block-diag strict upper triangle]
// N=16384 (128 graphs x 128), D=512.
// R9: i8 K-loop is barrier-latency-bound (R6->R7: 2x work/barrier = 1.63x).
// Amortize again over N: each block computes a 128x256 strip (tile pair
// sharing one A-stage): 32 MFMA + 48KB stage per barrier, 16640 barrier-iters
// (vs 33024). Diag tiles stay on the exact bf16 path (x==64 column). k_flag
// deleted: refine self-flags per pair. No cooperative launch (R8: capture-
// fragile and slower).
// ---------------------------------------------------------------------------

typedef __attribute__((ext_vector_type(8))) __bf16 bf16x8;
typedef __attribute__((ext_vector_type(16))) float floatx16;
typedef __attribute__((ext_vector_type(4))) int intx4;
typedef __attribute__((ext_vector_type(16))) int intx16;

#define AS1 __attribute__((address_space(1)))
#define AS3 __attribute__((address_space(3)))

static constexpr int DIM      = 512;
static constexpr int NTILE    = 128;
static constexpr int NPAIRIDX = 65 * 128;   // pair-slot space (x=64 -> diag)
static constexpr float QS     = 19.5f;      // i8 quant scale
static constexpr int MARGIN_I = 3042;       // 8 sims-units * QS^2

// ctrl: [0] fkey_min [1] fkey_max [2] i8 gmin

static __device__ __forceinline__ unsigned short f2bf_rne(float f) {
  unsigned int u = __float_as_uint(f);
  u += 0x7fffu + ((u >> 16) & 1u);
  return (unsigned short)(u >> 16);
}
static __device__ __forceinline__ int fkey(float f) {
  int s = __float_as_int(f);
  return s >= 0 ? s : (s ^ 0x7fffffff);
}
static __device__ __forceinline__ float funkey(int k) {
  return __int_as_float(k >= 0 ? k : (k ^ 0x7fffffff));
}
// i8 tile, BK=128: 8 chunks(16B)/row, row stride 128 B
static __device__ __forceinline__ int swzi(int row, int c8) {
  return c8 ^ (row & 7) ^ ((row >> 3) & 7);
}
// bf16 tile, BK=128 (diag): 16 chunks(16B)/row
static __device__ __forceinline__ int swzd(int row, int c16) {
  return c16 ^ (row & 15);
}
// bf16 tile, BK=64 (refine): 8 chunks(16B)/row
static __device__ __forceinline__ int swz8(int row, int c8) {
  return c8 ^ (row & 7);
}

// ---- kernel 1: fp32 -> bf16 + i8, init ctrl --------------------------------
__global__ void k_convert(const float* __restrict__ in,
                          unsigned short* __restrict__ bf,
                          char* __restrict__ q,
                          int* __restrict__ ctrl, int n4) {
  int i = blockIdx.x * blockDim.x + threadIdx.x;
  if (i == 0) {
    ctrl[0] = 0x7fffffff; ctrl[1] = (int)0x80000000;
    ctrl[2] = 0x7fffffff;
  }
  if (i >= n4) return;
  float4 v = ((const float4*)in)[i];
  ushort4 o;
  o.x = f2bf_rne(v.x); o.y = f2bf_rne(v.y);
  o.z = f2bf_rne(v.z); o.w = f2bf_rne(v.w);
  ((ushort4*)bf)[i] = o;
  int qx = __float2int_rn(v.x * QS), qy = __float2int_rn(v.y * QS);
  int qz = __float2int_rn(v.z * QS), qw = __float2int_rn(v.w * QS);
  char4 c;
  c.x = (char)min(127, max(-127, qx));
  c.y = (char)min(127, max(-127, qy));
  c.z = (char)min(127, max(-127, qz));
  c.w = (char)min(127, max(-127, qw));
  ((char4*)q)[i] = c;
}

// ---- kernel 2: GEMM --------------------------------------------------------
// grid (65, 128): x<64 -> i8 pair strip 128x256 at (tr=y, tc={2x,2x+1});
// x==64 -> bf16 exact diagonal tile tr=y.
__global__ __launch_bounds__(256) void k_gemm(
    const char* __restrict__ Eq,
    const unsigned short* __restrict__ E,
    int* __restrict__ ipart,
    float* __restrict__ diagblocks,
    int* __restrict__ ctrl) {
  const int x  = blockIdx.x;
  const int tr = blockIdx.y;
  const int pi = tr * 65 + x;

  const int tid = threadIdx.x;
  __shared__ __align__(16) char smem[3][16384];   // 48 KB
  __shared__ float2 redbuf[4];
  __shared__ int iredbuf[4];

  const int w = tid >> 6, lane = tid & 63;
  const int wr = w >> 1, wc = w & 1;
  const int l31 = lane & 31;
  const int kg  = lane >> 5;

  if (x < 64) {
    const int tc1 = 2 * x + 1;
    if (tc1 <= tr) {                 // pair entirely at/below diagonal
      if (tid == 0) ipart[pi] = 0x7fffffff;
      return;
    }
    const int tc0 = (2 * x > tr) ? 2 * x : tc1;   // dup tc1 if tc0 not off-diag

    char* lA  = smem[0];
    char* lB0 = smem[1];
    char* lB1 = smem[2];

    intx16 acc[2][2][2];             // [b][ti][tj]
#pragma unroll
    for (int b = 0; b < 2; b++)
#pragma unroll
      for (int i = 0; i < 2; i++)
#pragma unroll
        for (int j = 0; j < 2; j++)
#pragma unroll
          for (int r = 0; r < 16; r++) acc[b][i][j][r] = 0;

    const int rowBaseA  = tr * 128;
    const int rowBaseB0 = tc0 * 128;
    const int rowBaseB1 = tc1 * 128;

    for (int kb = 0; kb < 4; kb++) {              // K = 512 = 4 * BK(128)
      const int kBase = kb * 128;
#pragma unroll
      for (int j = 0; j < 4; j++) {
        int p   = (w * 4 + j) * 64 + lane;        // 0..1023 chunk id
        int row = p >> 3, c8 = p & 7;
        int sc8 = swzi(row, c8);
        int off = kBase + sc8 * 16;
        const char* gA  = Eq + (size_t)(rowBaseA  + row) * DIM + off;
        const char* gB0 = Eq + (size_t)(rowBaseB0 + row) * DIM + off;
        const char* gB1 = Eq + (size_t)(rowBaseB1 + row) * DIM + off;
        __builtin_amdgcn_global_load_lds((const AS1 unsigned int*)gA,
                                         (AS3 unsigned int*)(lA + p * 16), 16, 0, 0);
        __builtin_amdgcn_global_load_lds((const AS1 unsigned int*)gB0,
                                         (AS3 unsigned int*)(lB0 + p * 16), 16, 0, 0);
        __builtin_amdgcn_global_load_lds((const AS1 unsigned int*)gB1,
                                         (AS3 unsigned int*)(lB1 + p * 16), 16, 0, 0);
      }
      __syncthreads();

#pragma unroll
      for (int ks = 0; ks < 4; ks++) {            // 4 k-steps of 32
        intx4 af[2], b0v[2], b1v[2];
        const int c8 = ks * 2 + kg;
#pragma unroll
        for (int t = 0; t < 2; t++) {
          int ra = wr * 64 + t * 32 + l31;
          int rb = wc * 64 + t * 32 + l31;
          af[t]  = *(const intx4*)(lA  + ra * 128 + swzi(ra, c8) * 16);
          b0v[t] = *(const intx4*)(lB0 + rb * 128 + swzi(rb, c8) * 16);
          b1v[t] = *(const intx4*)(lB1 + rb * 128 + swzi(rb, c8) * 16);
        }
#pragma unroll
        for (int ti = 0; ti < 2; ti++)
#pragma unroll
          for (int tj = 0; tj < 2; tj++) {
            acc[0][ti][tj] = __builtin_amdgcn_mfma_i32_32x32x32_i8(
                af[ti], b0v[tj], acc[0][ti][tj], 0, 0, 0);
            acc[1][ti][tj] = __builtin_amdgcn_mfma_i32_32x32x32_i8(
                af[ti], b1v[tj], acc[1][ti][tj], 0, 0, 0);
          }
      }
      __syncthreads();
    }

    int vmin = 0x7fffffff;
#pragma unroll
    for (int b = 0; b < 2; b++)
#pragma unroll
      for (int ti = 0; ti < 2; ti++)
#pragma unroll
        for (int tj = 0; tj < 2; tj++)
#pragma unroll
          for (int r = 0; r < 16; r++) vmin = min(vmin, acc[b][ti][tj][r]);
#pragma unroll
    for (int m_ = 32; m_ >= 1; m_ >>= 1)
      vmin = min(vmin, __shfl_xor(vmin, m_));
    if (lane == 0) iredbuf[w] = vmin;
    __syncthreads();
    if (tid == 0) {
      int mn = iredbuf[0];
      for (int i = 1; i < 4; i++) mn = min(mn, iredbuf[i]);
      ipart[pi] = mn;
      atomicMin(&ctrl[2], mn);
    }
  } else {
    // ---- bf16 diagonal path (exact), BK=128, 32 KB of smem ----
    if (tid == 0) ipart[pi] = 0x7fffffff;        // never flagged
    unsigned short* lA = (unsigned short*)&smem[0][0];
    floatx16 acc[2][2];
#pragma unroll
    for (int i = 0; i < 2; i++)
#pragma unroll
      for (int j = 0; j < 2; j++)
#pragma unroll
        for (int r = 0; r < 16; r++) acc[i][j][r] = 0.f;

    const int rowBase = tr * 128;

    for (int kb = 0; kb < 4; kb++) {
      const int kBase = kb * 128;
#pragma unroll
      for (int j = 0; j < 8; j++) {
        int p   = (w * 8 + j) * 64 + lane;        // 0..2047 chunk id
        int row = p >> 4, c16 = p & 15;
        int sc = swzd(row, c16);
        const unsigned short* gA =
            E + (size_t)(rowBase + row) * DIM + kBase + sc * 8;
        __builtin_amdgcn_global_load_lds((const AS1 unsigned int*)gA,
                                         (AS3 unsigned int*)(lA + p * 8), 16, 0, 0);
      }
      __syncthreads();

#pragma unroll
      for (int ks = 0; ks < 8; ks++) {
        bf16x8 af[2], bfv[2];
        const int c16 = ks * 2 + kg;
#pragma unroll
        for (int t = 0; t < 2; t++) {
          int ra = wr * 64 + t * 32 + l31;
          int rb = wc * 64 + t * 32 + l31;
          af[t]  = *(const bf16x8*)(lA + ra * 128 + swzd(ra, c16) * 8);
          bfv[t] = *(const bf16x8*)(lA + rb * 128 + swzd(rb, c16) * 8);
        }
#pragma unroll
        for (int ti = 0; ti < 2; ti++)
#pragma unroll
          for (int tj = 0; tj < 2; tj++)
            acc[ti][tj] = __builtin_amdgcn_mfma_f32_32x32x16_bf16(
                af[ti], bfv[tj], acc[ti][tj], 0, 0, 0);
      }
      __syncthreads();
    }

    float vmin = 3.4e38f, vmax = -3.4e38f;
#pragma unroll
    for (int ti = 0; ti < 2; ti++)
#pragma unroll
      for (int tj = 0; tj < 2; tj++)
#pragma unroll
        for (int r = 0; r < 16; r++) {
          float v = acc[ti][tj][r];
          vmin = fminf(vmin, v);
          vmax = fmaxf(vmax, v);
        }
#pragma unroll
    for (int m_ = 32; m_ >= 1; m_ >>= 1) {
      vmin = fminf(vmin, __shfl_xor(vmin, m_));
      vmax = fmaxf(vmax, __shfl_xor(vmax, m_));
    }
    if (lane == 0) redbuf[w] = make_float2(vmin, vmax);
    __syncthreads();
    if (tid == 0) {
      float mn = redbuf[0].x, mx = redbuf[0].y;
      for (int i = 1; i < 4; i++) {
        mn = fminf(mn, redbuf[i].x);
        mx = fmaxf(mx, redbuf[i].y);
      }
      atomicMin(&ctrl[0], fkey(mn));
      atomicMax(&ctrl[1], fkey(mx));  // global max is diagonal (Cauchy-Schwarz)
    }

    float* Bout = diagblocks + (size_t)tr * (128 * 128);
#pragma unroll
    for (int ti = 0; ti < 2; ti++) {
#pragma unroll
      for (int tj = 0; tj < 2; tj++) {
        int cbase = wc * 64 + tj * 32 + l31;      // C/D: col = lane & 31
#pragma unroll
        for (int r = 0; r < 16; r++) {
          int row = wr * 64 + ti * 32 + (r & 3) + 8 * (r >> 2) + 4 * kg;
          Bout[row * 128 + cbase] = acc[ti][tj][r];
        }
      }
    }
  }
}

// ---- kernel 3: self-flagged bf16 refine (exact min of flagged pairs) -------
__global__ __launch_bounds__(256) void k_refine(
    const unsigned short* __restrict__ E,
    const int* __restrict__ ipart, int* __restrict__ ctrl) {
  const int pi = blockIdx.x;
  if (ipart[pi] > ctrl[2] + MARGIN_I) return;     // block-uniform
  const int tr = pi / 65, x = pi % 65;
  if (x == 64) return;                            // diag: exact already

  const int tid = threadIdx.x;
  __shared__ __align__(16) unsigned short lA[128 * 64];
  __shared__ __align__(16) unsigned short lB[128 * 64];
  __shared__ float redbuf[4];

  const int w = tid >> 6, lane = tid & 63;
  const int wr = w >> 1, wc = w & 1;
  const int l31 = lane & 31;
  const int kg  = lane >> 5;

  for (int s = 0; s < 2; s++) {
    const int tc = 2 * x + s;
    if (tc <= tr) continue;

    floatx16 acc[2][2];
#pragma unroll
    for (int i = 0; i < 2; i++)
#pragma unroll
      for (int j = 0; j < 2; j++)
#pragma unroll
        for (int r = 0; r < 16; r++) acc[i][j][r] = 0.f;

    const int rowBaseA = tr * 128;
    const int rowBaseB = tc * 128;

    for (int kb = 0; kb < 8; kb++) {              // BK=64
      const int kBase = kb * 64;
#pragma unroll
      for (int j = 0; j < 4; j++) {
        int cb  = (w * 4 + j) * 64;
        int p   = cb + lane;
        int row = p >> 3, c8 = p & 7;
        int sc8 = swz8(row, c8);
        const unsigned short* gA = E + (size_t)(rowBaseA + row) * DIM + kBase + sc8 * 8;
        const unsigned short* gB = E + (size_t)(rowBaseB + row) * DIM + kBase + sc8 * 8;
        __builtin_amdgcn_global_load_lds((const AS1 unsigned int*)gA,
                                         (AS3 unsigned int*)(lA + cb * 8), 16, 0, 0);
        __builtin_amdgcn_global_load_lds((const AS1 unsigned int*)gB,
                                         (AS3 unsigned int*)(lB + cb * 8), 16, 0, 0);
      }
      __syncthreads();

#pragma unroll
      for (int ks = 0; ks < 4; ks++) {
        bf16x8 af[2], bfv[2];
        const int c8 = ks * 2 + kg;
#pragma unroll
        for (int t = 0; t < 2; t++) {
          int ra = wr * 64 + t * 32 + l31;
          int rb = wc * 64 + t * 32 + l31;
          af[t]  = *(const bf16x8*)(lA + (ra * 8 + swz8(ra, c8)) * 8);
          bfv[t] = *(const bf16x8*)(lB + (rb * 8 + swz8(rb, c8)) * 8);
        }
#pragma unroll
        for (int ti = 0; ti < 2; ti++)
#pragma unroll
          for (int tj = 0; tj < 2; tj++)
            acc[ti][tj] = __builtin_amdgcn_mfma_f32_32x32x16_bf16(
                af[ti], bfv[tj], acc[ti][tj], 0, 0, 0);
      }
      __syncthreads();
    }

    float vmin = 3.4e38f;
#pragma unroll
    for (int ti = 0; ti < 2; ti++)
#pragma unroll
      for (int tj = 0; tj < 2; tj++)
#pragma unroll
        for (int r = 0; r < 16; r++) vmin = fminf(vmin, acc[ti][tj][r]);
#pragma unroll
    for (int m_ = 32; m_ >= 1; m_ >>= 1)
      vmin = fminf(vmin, __shfl_xor(vmin, m_));
    if (lane == 0) redbuf[w] = vmin;
    __syncthreads();
    if (tid == 0) {
      float mn = redbuf[0];
      for (int i = 1; i < 4; i++) mn = fminf(mn, redbuf[i]);
      atomicMin(&ctrl[0], fkey(mn));
    }
    __syncthreads();
  }
}

// ---- kernel 4: gather + normalize ------------------------------------------
__global__ __launch_bounds__(256) void k_gather(
    const int* __restrict__ rix, const int* __restrict__ cix,
    const float* __restrict__ blocks, const int* __restrict__ ctrl,
    float* __restrict__ out, int n) {
  int i = blockIdx.x * blockDim.x + threadIdx.x;
  if (i >= n) return;
  float m   = funkey(ctrl[0]);
  float M   = funkey(ctrl[1]);
  float inv = 1.0f / (M - m + 1e-7f);
  int r = rix[i], c = cix[i];
  int g = r >> 7;
  float v = blocks[((size_t)g << 14) + ((r & 127) << 7) + (c & 127)];
  out[i] = (v - m) * inv;
}

// ---------------------------------------------------------------------------
extern "C" void kernel_launch(void* const* d_in, const int* in_sizes, int n_in,
                              void* d_out, int out_size, void* d_ws, size_t ws_size,
                              hipStream_t stream) {
  const float* emb = (const float*)d_in[0];
  const int* rix   = (const int*)d_in[1];
  const int* cix   = (const int*)d_in[2];

  char* ws = (char*)d_ws;
  int* ctrl           = (int*)ws;                            // 12 B (pad 256)
  unsigned short* Ebf = (unsigned short*)(ws + 256);         // 16 MB
  char* Eq            = (char*)(ws + 256 + (16u << 20));     // 8 MB
  float* diagblocks   = (float*)(ws + 256 + (24u << 20));    // 8 MB
  int* ipart          = (int*)(ws + 256 + (32u << 20));      // 33 KB

  int n4 = in_sizes[0] / 4;            // 16384*512 / 4

  k_convert<<<(n4 + 255) / 256, 256, 0, stream>>>(emb, Ebf, Eq, ctrl, n4);

  k_gemm<<<dim3(65, 128), 256, 0, stream>>>(Eq, Ebf, ipart, diagblocks, ctrl);

  k_refine<<<NPAIRIDX, 256, 0, stream>>>(Ebf, ipart, ctrl);

  k_gather<<<(out_size + 255) / 256, 256, 0, stream>>>(rix, cix, diagblocks,
                                                       ctrl, (float*)d_out,
                                                       out_size);
}

// Round 10
// 191.059 us; speedup vs baseline: 1.0975x; 1.0123x over previous
//
#include <hip/hip_runtime.h>
#include <hip/hip_bf16.h>
#include <stdint.h>

// ---------------------------------------------------------------------------
// LinkPredictor: out = minmax_norm(E @ E^T)[block-diag strict upper triangle]
// N=16384 (128 graphs x 128), D=512.
// R10: R9 + XCD-stable grid. R9's grid (65,128) had 65 % 8 == 1, so the
// B-pair column residue each XCD saw drifted every tr row -> 215 MB L2 miss
// traffic (B-set invalidated per row + 8x A replication). Pad gridDim.x to 72
// (multiple of 8): x residue per XCD is now constant across the whole sweep;
// each XCD holds its 16 B-tiles (1 MB) in L2. Everything else identical to R9.
// ---------------------------------------------------------------------------

typedef __attribute__((ext_vector_type(8))) __bf16 bf16x8;
typedef __attribute__((ext_vector_type(16))) float floatx16;
typedef __attribute__((ext_vector_type(4))) int intx4;
typedef __attribute__((ext_vector_type(16))) int intx16;

#define AS1 __attribute__((address_space(1)))
#define AS3 __attribute__((address_space(3)))

static constexpr int DIM      = 512;
static constexpr int NTILE    = 128;
static constexpr int GX       = 72;         // padded grid x (multiple of 8)
static constexpr int NPAIRIDX = 65 * 128;   // pair-slot space (x=64 -> diag)
static constexpr float QS     = 19.5f;      // i8 quant scale
static constexpr int MARGIN_I = 3042;       // 8 sims-units * QS^2

// ctrl: [0] fkey_min [1] fkey_max [2] i8 gmin

static __device__ __forceinline__ unsigned short f2bf_rne(float f) {
  unsigned int u = __float_as_uint(f);
  u += 0x7fffu + ((u >> 16) & 1u);
  return (unsigned short)(u >> 16);
}
static __device__ __forceinline__ int fkey(float f) {
  int s = __float_as_int(f);
  return s >= 0 ? s : (s ^ 0x7fffffff);
}
static __device__ __forceinline__ float funkey(int k) {
  return __int_as_float(k >= 0 ? k : (k ^ 0x7fffffff));
}
// i8 tile, BK=128: 8 chunks(16B)/row, row stride 128 B
static __device__ __forceinline__ int swzi(int row, int c8) {
  return c8 ^ (row & 7) ^ ((row >> 3) & 7);
}
// bf16 tile, BK=128 (diag): 16 chunks(16B)/row
static __device__ __forceinline__ int swzd(int row, int c16) {
  return c16 ^ (row & 15);
}
// bf16 tile, BK=64 (refine): 8 chunks(16B)/row
static __device__ __forceinline__ int swz8(int row, int c8) {
  return c8 ^ (row & 7);
}

// ---- kernel 1: fp32 -> bf16 + i8, init ctrl --------------------------------
__global__ void k_convert(const float* __restrict__ in,
                          unsigned short* __restrict__ bf,
                          char* __restrict__ q,
                          int* __restrict__ ctrl, int n4) {
  int i = blockIdx.x * blockDim.x + threadIdx.x;
  if (i == 0) {
    ctrl[0] = 0x7fffffff; ctrl[1] = (int)0x80000000;
    ctrl[2] = 0x7fffffff;
  }
  if (i >= n4) return;
  float4 v = ((const float4*)in)[i];
  ushort4 o;
  o.x = f2bf_rne(v.x); o.y = f2bf_rne(v.y);
  o.z = f2bf_rne(v.z); o.w = f2bf_rne(v.w);
  ((ushort4*)bf)[i] = o;
  int qx = __float2int_rn(v.x * QS), qy = __float2int_rn(v.y * QS);
  int qz = __float2int_rn(v.z * QS), qw = __float2int_rn(v.w * QS);
  char4 c;
  c.x = (char)min(127, max(-127, qx));
  c.y = (char)min(127, max(-127, qy));
  c.z = (char)min(127, max(-127, qz));
  c.w = (char)min(127, max(-127, qw));
  ((char4*)q)[i] = c;
}

// ---- kernel 2: GEMM --------------------------------------------------------
// grid (72, 128): x<64 -> i8 pair strip 128x256 at (tr=y, tc={2x,2x+1});
// x==64 -> bf16 exact diagonal tile tr=y; x>64 -> padding, exit.
__global__ __launch_bounds__(256) void k_gemm(
    const char* __restrict__ Eq,
    const unsigned short* __restrict__ E,
    int* __restrict__ ipart,
    float* __restrict__ diagblocks,
    int* __restrict__ ctrl) {
  const int x  = blockIdx.x;
  const int tr = blockIdx.y;
  if (x > 64) return;                      // XCD-alignment padding
  const int pi = tr * 65 + x;

  const int tid = threadIdx.x;
  __shared__ __align__(16) char smem[3][16384];   // 48 KB
  __shared__ float2 redbuf[4];
  __shared__ int iredbuf[4];

  const int w = tid >> 6, lane = tid & 63;
  const int wr = w >> 1, wc = w & 1;
  const int l31 = lane & 31;
  const int kg  = lane >> 5;

  if (x < 64) {
    const int tc1 = 2 * x + 1;
    if (tc1 <= tr) {                 // pair entirely at/below diagonal
      if (tid == 0) ipart[pi] = 0x7fffffff;
      return;
    }
    const int tc0 = (2 * x > tr) ? 2 * x : tc1;   // dup tc1 if tc0 not off-diag

    char* lA  = smem[0];
    char* lB0 = smem[1];
    char* lB1 = smem[2];

    intx16 acc[2][2][2];             // [b][ti][tj]
#pragma unroll
    for (int b = 0; b < 2; b++)
#pragma unroll
      for (int i = 0; i < 2; i++)
#pragma unroll
        for (int j = 0; j < 2; j++)
#pragma unroll
          for (int r = 0; r < 16; r++) acc[b][i][j][r] = 0;

    const int rowBaseA  = tr * 128;
    const int rowBaseB0 = tc0 * 128;
    const int rowBaseB1 = tc1 * 128;

    for (int kb = 0; kb < 4; kb++) {              // K = 512 = 4 * BK(128)
      const int kBase = kb * 128;
#pragma unroll
      for (int j = 0; j < 4; j++) {
        int p   = (w * 4 + j) * 64 + lane;        // 0..1023 chunk id
        int row = p >> 3, c8 = p & 7;
        int sc8 = swzi(row, c8);
        int off = kBase + sc8 * 16;
        const char* gA  = Eq + (size_t)(rowBaseA  + row) * DIM + off;
        const char* gB0 = Eq + (size_t)(rowBaseB0 + row) * DIM + off;
        const char* gB1 = Eq + (size_t)(rowBaseB1 + row) * DIM + off;
        __builtin_amdgcn_global_load_lds((const AS1 unsigned int*)gA,
                                         (AS3 unsigned int*)(lA + p * 16), 16, 0, 0);
        __builtin_amdgcn_global_load_lds((const AS1 unsigned int*)gB0,
                                         (AS3 unsigned int*)(lB0 + p * 16), 16, 0, 0);
        __builtin_amdgcn_global_load_lds((const AS1 unsigned int*)gB1,
                                         (AS3 unsigned int*)(lB1 + p * 16), 16, 0, 0);
      }
      __syncthreads();

#pragma unroll
      for (int ks = 0; ks < 4; ks++) {            // 4 k-steps of 32
        intx4 af[2], b0v[2], b1v[2];
        const int c8 = ks * 2 + kg;
#pragma unroll
        for (int t = 0; t < 2; t++) {
          int ra = wr * 64 + t * 32 + l31;
          int rb = wc * 64 + t * 32 + l31;
          af[t]  = *(const intx4*)(lA  + ra * 128 + swzi(ra, c8) * 16);
          b0v[t] = *(const intx4*)(lB0 + rb * 128 + swzi(rb, c8) * 16);
          b1v[t] = *(const intx4*)(lB1 + rb * 128 + swzi(rb, c8) * 16);
        }
#pragma unroll
        for (int ti = 0; ti < 2; ti++)
#pragma unroll
          for (int tj = 0; tj < 2; tj++) {
            acc[0][ti][tj] = __builtin_amdgcn_mfma_i32_32x32x32_i8(
                af[ti], b0v[tj], acc[0][ti][tj], 0, 0, 0);
            acc[1][ti][tj] = __builtin_amdgcn_mfma_i32_32x32x32_i8(
                af[ti], b1v[tj], acc[1][ti][tj], 0, 0, 0);
          }
      }
      __syncthreads();
    }

    int vmin = 0x7fffffff;
#pragma unroll
    for (int b = 0; b < 2; b++)
#pragma unroll
      for (int ti = 0; ti < 2; ti++)
#pragma unroll
        for (int tj = 0; tj < 2; tj++)
#pragma unroll
          for (int r = 0; r < 16; r++) vmin = min(vmin, acc[b][ti][tj][r]);
#pragma unroll
    for (int m_ = 32; m_ >= 1; m_ >>= 1)
      vmin = min(vmin, __shfl_xor(vmin, m_));
    if (lane == 0) iredbuf[w] = vmin;
    __syncthreads();
    if (tid == 0) {
      int mn = iredbuf[0];
      for (int i = 1; i < 4; i++) mn = min(mn, iredbuf[i]);
      ipart[pi] = mn;
      atomicMin(&ctrl[2], mn);
    }
  } else {
    // ---- bf16 diagonal path (exact), BK=128, 32 KB of smem ----
    if (tid == 0) ipart[pi] = 0x7fffffff;        // never flagged
    unsigned short* lA = (unsigned short*)&smem[0][0];
    floatx16 acc[2][2];
#pragma unroll
    for (int i = 0; i < 2; i++)
#pragma unroll
      for (int j = 0; j < 2; j++)
#pragma unroll
        for (int r = 0; r < 16; r++) acc[i][j][r] = 0.f;

    const int rowBase = tr * 128;

    for (int kb = 0; kb < 4; kb++) {
      const int kBase = kb * 128;
#pragma unroll
      for (int j = 0; j < 8; j++) {
        int p   = (w * 8 + j) * 64 + lane;        // 0..2047 chunk id
        int row = p >> 4, c16 = p & 15;
        int sc = swzd(row, c16);
        const unsigned short* gA =
            E + (size_t)(rowBase + row) * DIM + kBase + sc * 8;
        __builtin_amdgcn_global_load_lds((const AS1 unsigned int*)gA,
                                         (AS3 unsigned int*)(lA + p * 8), 16, 0, 0);
      }
      __syncthreads();

#pragma unroll
      for (int ks = 0; ks < 8; ks++) {
        bf16x8 af[2], bfv[2];
        const int c16 = ks * 2 + kg;
#pragma unroll
        for (int t = 0; t < 2; t++) {
          int ra = wr * 64 + t * 32 + l31;
          int rb = wc * 64 + t * 32 + l31;
          af[t]  = *(const bf16x8*)(lA + ra * 128 + swzd(ra, c16) * 8);
          bfv[t] = *(const bf16x8*)(lA + rb * 128 + swzd(rb, c16) * 8);
        }
#pragma unroll
        for (int ti = 0; ti < 2; ti++)
#pragma unroll
          for (int tj = 0; tj < 2; tj++)
            acc[ti][tj] = __builtin_amdgcn_mfma_f32_32x32x16_bf16(
                af[ti], bfv[tj], acc[ti][tj], 0, 0, 0);
      }
      __syncthreads();
    }

    float vmin = 3.4e38f, vmax = -3.4e38f;
#pragma unroll
    for (int ti = 0; ti < 2; ti++)
#pragma unroll
      for (int tj = 0; tj < 2; tj++)
#pragma unroll
        for (int r = 0; r < 16; r++) {
          float v = acc[ti][tj][r];
          vmin = fminf(vmin, v);
          vmax = fmaxf(vmax, v);
        }
#pragma unroll
    for (int m_ = 32; m_ >= 1; m_ >>= 1) {
      vmin = fminf(vmin, __shfl_xor(vmin, m_));
      vmax = fmaxf(vmax, __shfl_xor(vmax, m_));
    }
    if (lane == 0) redbuf[w] = make_float2(vmin, vmax);
    __syncthreads();
    if (tid == 0) {
      float mn = redbuf[0].x, mx = redbuf[0].y;
      for (int i = 1; i < 4; i++) {
        mn = fminf(mn, redbuf[i].x);
        mx = fmaxf(mx, redbuf[i].y);
      }
      atomicMin(&ctrl[0], fkey(mn));
      atomicMax(&ctrl[1], fkey(mx));  // global max is diagonal (Cauchy-Schwarz)
    }

    float* Bout = diagblocks + (size_t)tr * (128 * 128);
#pragma unroll
    for (int ti = 0; ti < 2; ti++) {
#pragma unroll
      for (int tj = 0; tj < 2; tj++) {
        int cbase = wc * 64 + tj * 32 + l31;      // C/D: col = lane & 31
#pragma unroll
        for (int r = 0; r < 16; r++) {
          int row = wr * 64 + ti * 32 + (r & 3) + 8 * (r >> 2) + 4 * kg;
          Bout[row * 128 + cbase] = acc[ti][tj][r];
        }
      }
    }
  }
}

// ---- kernel 3: self-flagged bf16 refine (exact min of flagged pairs) -------
__global__ __launch_bounds__(256) void k_refine(
    const unsigned short* __restrict__ E,
    const int* __restrict__ ipart, int* __restrict__ ctrl) {
  const int pi = blockIdx.x;
  if (ipart[pi] > ctrl[2] + MARGIN_I) return;     // block-uniform
  const int tr = pi / 65, x = pi % 65;
  if (x == 64) return;                            // diag: exact already

  const int tid = threadIdx.x;
  __shared__ __align__(16) unsigned short lA[128 * 64];
  __shared__ __align__(16) unsigned short lB[128 * 64];
  __shared__ float redbuf[4];

  const int w = tid >> 6, lane = tid & 63;
  const int wr = w >> 1, wc = w & 1;
  const int l31 = lane & 31;
  const int kg  = lane >> 5;

  for (int s = 0; s < 2; s++) {
    const int tc = 2 * x + s;
    if (tc <= tr) continue;

    floatx16 acc[2][2];
#pragma unroll
    for (int i = 0; i < 2; i++)
#pragma unroll
      for (int j = 0; j < 2; j++)
#pragma unroll
        for (int r = 0; r < 16; r++) acc[i][j][r] = 0.f;

    const int rowBaseA = tr * 128;
    const int rowBaseB = tc * 128;

    for (int kb = 0; kb < 8; kb++) {              // BK=64
      const int kBase = kb * 64;
#pragma unroll
      for (int j = 0; j < 4; j++) {
        int cb  = (w * 4 + j) * 64;
        int p   = cb + lane;
        int row = p >> 3, c8 = p & 7;
        int sc8 = swz8(row, c8);
        const unsigned short* gA = E + (size_t)(rowBaseA + row) * DIM + kBase + sc8 * 8;
        const unsigned short* gB = E + (size_t)(rowBaseB + row) * DIM + kBase + sc8 * 8;
        __builtin_amdgcn_global_load_lds((const AS1 unsigned int*)gA,
                                         (AS3 unsigned int*)(lA + cb * 8), 16, 0, 0);
        __builtin_amdgcn_global_load_lds((const AS1 unsigned int*)gB,
                                         (AS3 unsigned int*)(lB + cb * 8), 16, 0, 0);
      }
      __syncthreads();

#pragma unroll
      for (int ks = 0; ks < 4; ks++) {
        bf16x8 af[2], bfv[2];
        const int c8 = ks * 2 + kg;
#pragma unroll
        for (int t = 0; t < 2; t++) {
          int ra = wr * 64 + t * 32 + l31;
          int rb = wc * 64 + t * 32 + l31;
          af[t]  = *(const bf16x8*)(lA + (ra * 8 + swz8(ra, c8)) * 8);
          bfv[t] = *(const bf16x8*)(lB + (rb * 8 + swz8(rb, c8)) * 8);
        }
#pragma unroll
        for (int ti = 0; ti < 2; ti++)
#pragma unroll
          for (int tj = 0; tj < 2; tj++)
            acc[ti][tj] = __builtin_amdgcn_mfma_f32_32x32x16_bf16(
                af[ti], bfv[tj], acc[ti][tj], 0, 0, 0);
      }
      __syncthreads();
    }

    float vmin = 3.4e38f;
#pragma unroll
    for (int ti = 0; ti < 2; ti++)
#pragma unroll
      for (int tj = 0; tj < 2; tj++)
#pragma unroll
        for (int r = 0; r < 16; r++) vmin = fminf(vmin, acc[ti][tj][r]);
#pragma unroll
    for (int m_ = 32; m_ >= 1; m_ >>= 1)
      vmin = fminf(vmin, __shfl_xor(vmin, m_));
    if (lane == 0) redbuf[w] = vmin;
    __syncthreads();
    if (tid == 0) {
      float mn = redbuf[0];
      for (int i = 1; i < 4; i++) mn = fminf(mn, redbuf[i]);
      atomicMin(&ctrl[0], fkey(mn));
    }
    __syncthreads();
  }
}

// ---- kernel 4: gather + normalize ------------------------------------------
__global__ __launch_bounds__(256) void k_gather(
    const int* __restrict__ rix, const int* __restrict__ cix,
    const float* __restrict__ blocks, const int* __restrict__ ctrl,
    float* __restrict__ out, int n) {
  int i = blockIdx.x * blockDim.x + threadIdx.x;
  if (i >= n) return;
  float m   = funkey(ctrl[0]);
  float M   = funkey(ctrl[1]);
  float inv = 1.0f / (M - m + 1e-7f);
  int r = rix[i], c = cix[i];
  int g = r >> 7;
  float v = blocks[((size_t)g << 14) + ((r & 127) << 7) + (c & 127)];
  out[i] = (v - m) * inv;
}

// ---------------------------------------------------------------------------
extern "C" void kernel_launch(void* const* d_in, const int* in_sizes, int n_in,
                              void* d_out, int out_size, void* d_ws, size_t ws_size,
                              hipStream_t stream) {
  const float* emb = (const float*)d_in[0];
  const int* rix   = (const int*)d_in[1];
  const int* cix   = (const int*)d_in[2];

  char* ws = (char*)d_ws;
  int* ctrl           = (int*)ws;                            // 12 B (pad 256)
  unsigned short* Ebf = (unsigned short*)(ws + 256);         // 16 MB
  char* Eq            = (char*)(ws + 256 + (16u << 20));     // 8 MB
  float* diagblocks   = (float*)(ws + 256 + (24u << 20));    // 8 MB
  int* ipart          = (int*)(ws + 256 + (32u << 20));      // 33 KB

  int n4 = in_sizes[0] / 4;            // 16384*512 / 4

  k_convert<<<(n4 + 255) / 256, 256, 0, stream>>>(emb, Ebf, Eq, ctrl, n4);

  k_gemm<<<dim3(GX, 128), 256, 0, stream>>>(Eq, Ebf, ipart, diagblocks, ctrl);

  k_refine<<<NPAIRIDX, 256, 0, stream>>>(Ebf, ipart, ctrl);

  k_gather<<<(out_size + 255) / 256, 256, 0, stream>>>(rix, cix, diagblocks,
                                                       ctrl, (float*)d_out,
                                                       out_size);
}